// Round 1
// baseline (341.219 us; speedup 1.0000x reference)
//
#include <hip/hip_runtime.h>
#include <hip/hip_bf16.h>

typedef __attribute__((ext_vector_type(8))) __bf16 bf16x8;
typedef __attribute__((ext_vector_type(8))) unsigned short u16x8;
typedef __attribute__((ext_vector_type(4))) float f32x4;

#define MFMA_BF16(a,b,c) __builtin_amdgcn_mfma_f32_16x16x32_bf16((a),(b),(c),0,0,0)

#define DIMD 256
#define NHEAD 4
#define HDIM 64
#define ASCALE 0.125f
#define SEQT 512
#define NB 32
#define BT 16384  // NB*SEQT

__device__ __forceinline__ unsigned short f2bf(float f) {
    unsigned int u = __float_as_uint(f);
    u += 0x7fffu + ((u >> 16) & 1u);
    return (unsigned short)(u >> 16);
}
__device__ __forceinline__ float bf2f(unsigned short h) {
    return __uint_as_float(((unsigned int)h) << 16);
}

// ---------- cast x (fp32 -> bf16), 4 elems/thread ----------
__global__ __launch_bounds__(256) void cast_x_kernel(const float* __restrict__ x,
                                                     unsigned short* __restrict__ xb, int n) {
    int i = (blockIdx.x * 256 + threadIdx.x) * 4;
    if (i < n) {
        float4 v = *(const float4*)(x + i);
        ushort4 o;
        o.x = f2bf(v.x); o.y = f2bf(v.y); o.z = f2bf(v.z); o.w = f2bf(v.w);
        *(ushort4*)(xb + i) = o;
    }
}

// ---------- weight convert + transpose: src (K x 256) fp32 -> dst (256 x K) bf16 ----------
// launch <<<K, 256>>>
__global__ __launch_bounds__(256) void wconv_kernel(const float* __restrict__ src,
                                                    unsigned short* __restrict__ dst, int K) {
    int k = blockIdx.x, n = threadIdx.x;
    dst[(size_t)n * K + k] = f2bf(src[(size_t)k * 256 + n]);
}

// ---------- GEMM: C = A(MxK bf16, lda=K) * Bt(NxK bf16)^T + bias; tile 64x64, 4 waves ----------
// mode 0: bf16 out; mode 1: fp32 out (+resid if non-null). relu applied before store.
__global__ __launch_bounds__(256)
void gemm_nt(const unsigned short* __restrict__ A, const unsigned short* __restrict__ Bt,
             const float* __restrict__ bias, int K,
             void* __restrict__ out, int ldc, int mode, int do_relu,
             const float* __restrict__ resid) {
    __shared__ __align__(16) unsigned short As[64][40];
    __shared__ __align__(16) unsigned short Bs[64][40];
    const int tid = threadIdx.x;
    const int w = tid >> 6, l = tid & 63, g = l >> 4, rl = l & 15;
    const int m0 = blockIdx.x * 64, n0 = blockIdx.y * 64;
    const int arow = tid >> 2, akc = tid & 3;

    f32x4 acc[4];
    #pragma unroll
    for (int n = 0; n < 4; ++n) acc[n] = (f32x4){0.f, 0.f, 0.f, 0.f};

    for (int k0 = 0; k0 < K; k0 += 32) {
        u16x8 va = *(const u16x8*)(A  + (size_t)(m0 + arow) * K + k0 + akc * 8);
        u16x8 vb = *(const u16x8*)(Bt + (size_t)(n0 + arow) * K + k0 + akc * 8);
        __syncthreads();
        *(u16x8*)&As[arow][akc * 8] = va;
        *(u16x8*)&Bs[arow][akc * 8] = vb;
        __syncthreads();
        bf16x8 af = *(const bf16x8*)&As[w * 16 + rl][g * 8];
        #pragma unroll
        for (int n = 0; n < 4; ++n) {
            bf16x8 bfr = *(const bf16x8*)&Bs[n * 16 + rl][g * 8];
            acc[n] = MFMA_BF16(af, bfr, acc[n]);
        }
    }

    #pragma unroll
    for (int n = 0; n < 4; ++n) {
        #pragma unroll
        for (int r = 0; r < 4; ++r) {
            int row = m0 + w * 16 + g * 4 + r;
            int col = n0 + n * 16 + rl;
            float v = acc[n][r] + bias[col];
            if (do_relu) v = fmaxf(v, 0.f);
            if (mode == 0) {
                ((unsigned short*)out)[(size_t)row * ldc + col] = f2bf(v);
            } else {
                float res = resid ? resid[(size_t)row * 256 + col] : 0.f;
                ((float*)out)[(size_t)row * ldc + col] = v + res;
            }
        }
    }
}

// ---------- global attention: flash-style, block = (64 q-rows) x (1 b,h); 4 waves ----------
__global__ __launch_bounds__(256)
void attn_global(const unsigned short* __restrict__ qb, const unsigned short* __restrict__ kb,
                 const unsigned short* __restrict__ vb, const float* __restrict__ rpb,
                 unsigned short* __restrict__ gout) {
    __shared__ __align__(16) unsigned short Ks[64][72];
    __shared__ __align__(16) unsigned short Vt[64][72];
    __shared__ __align__(16) unsigned short Ps[64][72];
    __shared__ float rb_s[127];

    const int tid = threadIdx.x;
    const int w = tid >> 6, l = tid & 63, g = l >> 4, rl = l & 15;
    const int bh = blockIdx.y, b = bh >> 2, h = bh & 3;
    const int t0 = blockIdx.x * 64;
    const size_t base = (size_t)b * SEQT * 256 + h * 64;

    bf16x8 qf[2];
    #pragma unroll
    for (int kk = 0; kk < 2; ++kk)
        qf[kk] = *(const bf16x8*)(qb + base + (size_t)(t0 + w * 16 + rl) * 256 + kk * 32 + g * 8);

    f32x4 oacc[4];
    #pragma unroll
    for (int n = 0; n < 4; ++n) oacc[n] = (f32x4){0.f, 0.f, 0.f, 0.f};
    float m_run[4], l_run[4];
    #pragma unroll
    for (int r = 0; r < 4; ++r) { m_run[r] = -1e30f; l_run[r] = 0.f; }

    for (int s0 = 0; s0 < SEQT; s0 += 64) {
        __syncthreads();
        #pragma unroll
        for (int cc = 0; cc < 2; ++cc) {
            int c = tid + cc * 256;
            int sr = c >> 3, hc = c & 7;
            u16x8 kv = *(const u16x8*)(kb + base + (size_t)(s0 + sr) * 256 + hc * 8);
            u16x8 vv = *(const u16x8*)(vb + base + (size_t)(s0 + sr) * 256 + hc * 8);
            *(u16x8*)&Ks[sr][hc * 8] = kv;
            #pragma unroll
            for (int i = 0; i < 8; ++i) Vt[hc * 8 + i][sr] = (unsigned short)vv[i];
        }
        if (tid < 127) {
            int dd = s0 - t0 + 448 + tid;  // (s0 - t0 + 511 - 63 + tid)
            rb_s[tid] = rpb[dd * 4 + h];
        }
        __syncthreads();

        // S = Q K^T
        f32x4 sacc[4];
        #pragma unroll
        for (int n = 0; n < 4; ++n) sacc[n] = (f32x4){0.f, 0.f, 0.f, 0.f};
        #pragma unroll
        for (int kk = 0; kk < 2; ++kk) {
            #pragma unroll
            for (int n = 0; n < 4; ++n) {
                bf16x8 kf = *(const bf16x8*)&Ks[n * 16 + rl][kk * 32 + g * 8];
                sacc[n] = MFMA_BF16(qf[kk], kf, sacc[n]);
            }
        }

        // scale + rel-pos bias; online softmax
        float sv[4][4];
        float mt[4];
        #pragma unroll
        for (int r = 0; r < 4; ++r) mt[r] = -1e30f;
        #pragma unroll
        for (int n = 0; n < 4; ++n) {
            #pragma unroll
            for (int r = 0; r < 4; ++r) {
                int relc = (n * 16 + rl) - (w * 16 + g * 4 + r) + 63;
                float s = sacc[n][r] * ASCALE + rb_s[relc];
                sv[n][r] = s;
                mt[r] = fmaxf(mt[r], s);
            }
        }
        #pragma unroll
        for (int r = 0; r < 4; ++r) {
            #pragma unroll
            for (int mk = 1; mk < 16; mk <<= 1) mt[r] = fmaxf(mt[r], __shfl_xor(mt[r], mk));
        }
        float sf[4], rs[4];
        #pragma unroll
        for (int r = 0; r < 4; ++r) {
            float mn = fmaxf(m_run[r], mt[r]);
            sf[r] = expf(m_run[r] - mn);
            m_run[r] = mn;
            rs[r] = 0.f;
        }
        #pragma unroll
        for (int n = 0; n < 4; ++n) {
            #pragma unroll
            for (int r = 0; r < 4; ++r) {
                float p = expf(sv[n][r] - m_run[r]);
                rs[r] += p;
                Ps[w * 16 + g * 4 + r][n * 16 + rl] = f2bf(p);
            }
        }
        #pragma unroll
        for (int r = 0; r < 4; ++r) {
            #pragma unroll
            for (int mk = 1; mk < 16; mk <<= 1) rs[r] += __shfl_xor(rs[r], mk);
            l_run[r] = l_run[r] * sf[r] + rs[r];
        }
        #pragma unroll
        for (int n = 0; n < 4; ++n) {
            #pragma unroll
            for (int r = 0; r < 4; ++r) oacc[n][r] *= sf[r];
        }

        // O += P V  (P via LDS, wave-local rows: no barrier needed)
        #pragma unroll
        for (int kk = 0; kk < 2; ++kk) {
            bf16x8 pf = *(const bf16x8*)&Ps[w * 16 + rl][kk * 32 + g * 8];
            #pragma unroll
            for (int n = 0; n < 4; ++n) {
                bf16x8 vf = *(const bf16x8*)&Vt[n * 16 + rl][kk * 32 + g * 8];
                oacc[n] = MFMA_BF16(pf, vf, oacc[n]);
            }
        }
    }

    #pragma unroll
    for (int n = 0; n < 4; ++n) {
        #pragma unroll
        for (int r = 0; r < 4; ++r) {
            float o = oacc[n][r] / l_run[r];
            gout[base + (size_t)(t0 + w * 16 + g * 4 + r) * 256 + n * 16 + rl] = f2bf(o);
        }
    }
}

// ---------- local windowed attention: 1 wave per t, 4 waves/block ----------
__global__ __launch_bounds__(256)
void local_attn(const unsigned short* __restrict__ lqb, const unsigned short* __restrict__ lkb,
                const unsigned short* __restrict__ lvb,
                const float* __restrict__ lk_bias, const float* __restrict__ lv_bias,
                unsigned short* __restrict__ fused) {
    const int tid = threadIdx.x;
    const int wv = tid >> 6, lane = tid & 63;
    const int row = blockIdx.x * 4 + wv;
    const int b = row >> 9, tt = row & 511;

    ushort4 qv = *((const ushort4*)(lqb + (size_t)row * 256) + lane);
    float qf[4] = {bf2f(qv.x), bf2f(qv.y), bf2f(qv.z), bf2f(qv.w)};

    float sw[10];
    #pragma unroll
    for (int w = 0; w < 10; ++w) {
        int src = tt + w - 5;
        float kf[4];
        if (src >= 0 && src < 512) {
            ushort4 kv = *((const ushort4*)(lkb + (size_t)(b * 512 + src) * 256) + lane);
            kf[0] = bf2f(kv.x); kf[1] = bf2f(kv.y); kf[2] = bf2f(kv.z); kf[3] = bf2f(kv.w);
        } else {
            float4 kb4 = *((const float4*)lk_bias + lane);
            kf[0] = kb4.x; kf[1] = kb4.y; kf[2] = kb4.z; kf[3] = kb4.w;
        }
        float p = qf[0] * kf[0] + qf[1] * kf[1] + qf[2] * kf[2] + qf[3] * kf[3];
        #pragma unroll
        for (int mk = 1; mk < 64; mk <<= 1) p += __shfl_xor(p, mk);
        sw[w] = p * ASCALE;
    }
    float mx = sw[0];
    #pragma unroll
    for (int w = 1; w < 10; ++w) mx = fmaxf(mx, sw[w]);
    float pv[10], s = 0.f;
    #pragma unroll
    for (int w = 0; w < 10; ++w) { pv[w] = expf(sw[w] - mx); s += pv[w]; }
    float inv = 1.f / s;

    float of[4] = {0.f, 0.f, 0.f, 0.f};
    #pragma unroll
    for (int w = 0; w < 10; ++w) {
        int src = tt + w - 5;
        float vf[4];
        if (src >= 0 && src < 512) {
            ushort4 vv = *((const ushort4*)(lvb + (size_t)(b * 512 + src) * 256) + lane);
            vf[0] = bf2f(vv.x); vf[1] = bf2f(vv.y); vf[2] = bf2f(vv.z); vf[3] = bf2f(vv.w);
        } else {
            float4 vb4 = *((const float4*)lv_bias + lane);
            vf[0] = vb4.x; vf[1] = vb4.y; vf[2] = vb4.z; vf[3] = vb4.w;
        }
        float pw = pv[w] * inv;
        of[0] += pw * vf[0]; of[1] += pw * vf[1]; of[2] += pw * vf[2]; of[3] += pw * vf[3];
    }
    ushort4 o;
    o.x = f2bf(of[0]); o.y = f2bf(of[1]); o.z = f2bf(of[2]); o.w = f2bf(of[3]);
    *((ushort4*)(fused + (size_t)row * 512 + 256) + lane) = o;
}

// ---------- pooled mean over T ----------
__global__ __launch_bounds__(256)
void pooled_mean(const float* __restrict__ x, float* __restrict__ pooled) {
    int b = blockIdx.x, d = threadIdx.x;
    const float* xp = x + (size_t)b * SEQT * 256 + d;
    float s = 0.f;
    for (int t = 0; t < SEQT; ++t) s += xp[(size_t)t * 256];
    pooled[b * 256 + d] = s * (1.0f / 512.0f);
}

// ---------- pattern scores (all fp32) ----------
__global__ __launch_bounds__(256)
void pattern_k(const float* __restrict__ pooled, const float* __restrict__ pe,
               const float* __restrict__ pq_w, const float* __restrict__ pq_b,
               const float* __restrict__ pk_w, const float* __restrict__ pk_b,
               float* __restrict__ out_scores) {
    __shared__ float pool_s[256];
    __shared__ float pes[3 * 256];
    __shared__ float pq_s[256];
    __shared__ float pk_s[3][256];
    __shared__ float pw_s[4][3];
    int b = blockIdx.x, d = threadIdx.x;
    pool_s[d] = pooled[b * 256 + d];
    pes[d] = pe[d]; pes[256 + d] = pe[256 + d]; pes[512 + d] = pe[512 + d];
    __syncthreads();
    float acc = pq_b[d];
    for (int k = 0; k < 256; ++k) acc += pool_s[k] * pq_w[k * 256 + d];
    pq_s[d] = acc;
    for (int j = 0; j < 3; ++j) {
        float a = pk_b[d];
        for (int k = 0; k < 256; ++k) a += pes[j * 256 + k] * pk_w[k * 256 + d];
        pk_s[j][d] = a;
    }
    __syncthreads();
    int h = d >> 6, lane = d & 63;
    float lg[3];
    #pragma unroll
    for (int j = 0; j < 3; ++j) {
        float p = pq_s[h * 64 + lane] * pk_s[j][h * 64 + lane];
        #pragma unroll
        for (int mk = 1; mk < 64; mk <<= 1) p += __shfl_xor(p, mk);
        lg[j] = p * ASCALE;
    }
    float mx = fmaxf(fmaxf(lg[0], lg[1]), lg[2]);
    float e0 = expf(lg[0] - mx), e1 = expf(lg[1] - mx), e2 = expf(lg[2] - mx);
    float sinv = 1.f / (e0 + e1 + e2);
    if (lane == 0) { pw_s[h][0] = e0 * sinv; pw_s[h][1] = e1 * sinv; pw_s[h][2] = e2 * sinv; }
    __syncthreads();
    if (d < 3)
        out_scores[b * 3 + d] = 0.25f * (pw_s[0][d] + pw_s[1][d] + pw_s[2][d] + pw_s[3][d]);
}

extern "C" void kernel_launch(void* const* d_in, const int* in_sizes, int n_in,
                              void* d_out, int out_size, void* d_ws, size_t ws_size,
                              hipStream_t stream) {
    (void)in_sizes; (void)n_in; (void)out_size; (void)ws_size;
    const float* x    = (const float*)d_in[0];
    const float* gq_w = (const float*)d_in[1];  const float* gq_b = (const float*)d_in[2];
    const float* gk_w = (const float*)d_in[3];  const float* gk_b = (const float*)d_in[4];
    const float* gv_w = (const float*)d_in[5];  const float* gv_b = (const float*)d_in[6];
    const float* go_w = (const float*)d_in[7];  const float* go_b = (const float*)d_in[8];
    const float* rpb  = (const float*)d_in[9];
    const float* lq_w = (const float*)d_in[10]; const float* lq_b = (const float*)d_in[11];
    const float* lk_w = (const float*)d_in[12]; const float* lk_b = (const float*)d_in[13];
    const float* lv_w = (const float*)d_in[14]; const float* lv_b = (const float*)d_in[15];
    const float* pe   = (const float*)d_in[16];
    const float* pq_w = (const float*)d_in[17]; const float* pq_b = (const float*)d_in[18];
    const float* pk_w = (const float*)d_in[19]; const float* pk_b = (const float*)d_in[20];
    const float* f1_w = (const float*)d_in[21]; const float* f1_b = (const float*)d_in[22];
    const float* f2_w = (const float*)d_in[23]; const float* f2_b = (const float*)d_in[24];

    char* ws = (char*)d_ws;
    const size_t MB = 1024 * 1024;
    unsigned short* xb    = (unsigned short*)(ws + 0);          // also reused as g_out
    unsigned short* qb    = (unsigned short*)(ws + 8 * MB);
    unsigned short* kbuf  = (unsigned short*)(ws + 16 * MB);
    unsigned short* vbuf  = (unsigned short*)(ws + 24 * MB);
    unsigned short* lqb   = (unsigned short*)(ws + 32 * MB);
    unsigned short* lkb   = (unsigned short*)(ws + 40 * MB);
    unsigned short* lvb   = (unsigned short*)(ws + 48 * MB);
    unsigned short* fused = (unsigned short*)(ws + 56 * MB);    // 16384 x 512 bf16
    unsigned short* hb    = (unsigned short*)(ws + 72 * MB);
    unsigned short* wts   = (unsigned short*)(ws + 80 * MB);
    unsigned short* gq_t = wts;
    unsigned short* gk_t = gq_t + 65536;
    unsigned short* gv_t = gk_t + 65536;
    unsigned short* go_t = gv_t + 65536;
    unsigned short* lq_t = go_t + 65536;
    unsigned short* lk_t = lq_t + 65536;
    unsigned short* lv_t = lk_t + 65536;
    unsigned short* f1_t = lv_t + 65536;            // 256 x 512
    unsigned short* f2_t = f1_t + 131072;
    float* pooled = (float*)(ws + 82 * MB);

    float* out = (float*)d_out;
    float* out_scores = out + (size_t)BT * 256;

    // 1. casts / weight transposes
    cast_x_kernel<<<4096, 256, 0, stream>>>(x, xb, BT * 256);
    wconv_kernel<<<256, 256, 0, stream>>>(gq_w, gq_t, 256);
    wconv_kernel<<<256, 256, 0, stream>>>(gk_w, gk_t, 256);
    wconv_kernel<<<256, 256, 0, stream>>>(gv_w, gv_t, 256);
    wconv_kernel<<<256, 256, 0, stream>>>(go_w, go_t, 256);
    wconv_kernel<<<256, 256, 0, stream>>>(lq_w, lq_t, 256);
    wconv_kernel<<<256, 256, 0, stream>>>(lk_w, lk_t, 256);
    wconv_kernel<<<256, 256, 0, stream>>>(lv_w, lv_t, 256);
    wconv_kernel<<<512, 256, 0, stream>>>(f1_w, f1_t, 512);
    wconv_kernel<<<256, 256, 0, stream>>>(f2_w, f2_t, 256);

    dim3 ggrid(BT / 64, 4);
    // 2. projections
    gemm_nt<<<ggrid, 256, 0, stream>>>(xb, gq_t, gq_b, 256, qb,   256, 0, 0, nullptr);
    gemm_nt<<<ggrid, 256, 0, stream>>>(xb, gk_t, gk_b, 256, kbuf, 256, 0, 0, nullptr);
    gemm_nt<<<ggrid, 256, 0, stream>>>(xb, gv_t, gv_b, 256, vbuf, 256, 0, 0, nullptr);
    gemm_nt<<<ggrid, 256, 0, stream>>>(xb, lq_t, lq_b, 256, lqb,  256, 0, 0, nullptr);
    gemm_nt<<<ggrid, 256, 0, stream>>>(xb, lk_t, lk_b, 256, lkb,  256, 0, 0, nullptr);
    gemm_nt<<<ggrid, 256, 0, stream>>>(xb, lv_t, lv_b, 256, lvb,  256, 0, 0, nullptr);

    // 3. global attention -> g_out (reuses xb region)
    attn_global<<<dim3(SEQT / 64, NB * NHEAD), 256, 0, stream>>>(qb, kbuf, vbuf, rpb, xb);

    // 4. output proj into fused[:, 0:256]
    gemm_nt<<<ggrid, 256, 0, stream>>>(xb, go_t, go_b, 256, fused, 512, 0, 0, nullptr);

    // 5. local attention into fused[:, 256:512]
    local_attn<<<BT / 4, 256, 0, stream>>>(lqb, lkb, lvb, lk_b, lv_b, fused);

    // 6. FFN
    gemm_nt<<<ggrid, 256, 0, stream>>>(fused, f1_t, f1_b, 512, hb, 256, 0, 1, nullptr);
    gemm_nt<<<ggrid, 256, 0, stream>>>(hb, f2_t, f2_b, 256, out, 256, 1, 0, x);

    // 7. pattern path
    pooled_mean<<<NB, 256, 0, stream>>>(x, pooled);
    pattern_k<<<NB, 256, 0, stream>>>(pooled, pe, pq_w, pq_b, pk_w, pk_b, out_scores);
}